// Round 1
// baseline (234.570 us; speedup 1.0000x reference)
//
#include <hip/hip_runtime.h>

#define NTEST  16384
#define NTRAIN 8192
#define DIM    64
#define TCHUNK 512                   // train points per block
#define NCHUNK (NTRAIN / TCHUNK)     // 16

// One thread = one test point. Block = 256 threads (4 waves).
// Grid = (NTEST/256, NCHUNK). Each block handles a 256-test x 512-train tile.
// Partial sums combined with atomicAdd into d_out (zeroed via memsetAsync).
__global__ __launch_bounds__(256, 4) void krr_main(
    const float* __restrict__ test_X,
    const float* __restrict__ train_X,
    const float* __restrict__ alphas,
    const float* __restrict__ lengthscale,
    float* __restrict__ out)
{
    __shared__ float nt_lds[TCHUNK];  // scaled train norms for this chunk
    __shared__ float al_lds[TCHUNK];  // alphas for this chunk

    const int tid = threadIdx.x;
    const int i   = blockIdx.x * 256 + tid;
    const int j0  = blockIdx.y * TCHUNK;

    const float ls   = lengthscale[0];
    const float inv2 = 1.0f / (ls * ls);

    // Stage scaled train norms + alphas for this chunk into LDS (one-time).
    for (int jj = tid; jj < TCHUNK; jj += 256) {
        const float4* tr = reinterpret_cast<const float4*>(train_X + (size_t)(j0 + jj) * DIM);
        float s = 0.f;
        #pragma unroll
        for (int k = 0; k < DIM / 4; ++k) {
            float4 t = tr[k];
            s += t.x * t.x + t.y * t.y + t.z * t.z + t.w * t.w;
        }
        nt_lds[jj] = s * inv2;
        al_lds[jj] = alphas[j0 + jj];
    }
    __syncthreads();

    // Load this thread's test point into registers, pre-scaled by 1/ls^2 so
    // dot(xr, t_raw) = (x.t)/ls^2.
    float xr[DIM];
    float nx = 0.f;
    {
        const float4* xp = reinterpret_cast<const float4*>(test_X + (size_t)i * DIM);
        #pragma unroll
        for (int k = 0; k < DIM / 4; ++k) {
            float4 v = xp[k];
            xr[4 * k + 0] = v.x; xr[4 * k + 1] = v.y;
            xr[4 * k + 2] = v.z; xr[4 * k + 3] = v.w;
            nx += v.x * v.x + v.y * v.y + v.z * v.z + v.w * v.w;
        }
        nx *= inv2;
        #pragma unroll
        for (int k = 0; k < DIM; ++k) xr[k] *= inv2;
    }

    float acc = 0.f;
    for (int jj = 0; jj < TCHUNK; ++jj) {
        // Wave-uniform row pointer -> compiler should emit scalar (s_load) reads,
        // keeping the inner loop at 1 VALU FMA per element.
        const float* trow = train_X + (size_t)(j0 + jj) * DIM;
        float d0 = 0.f, d1 = 0.f, d2 = 0.f, d3 = 0.f;
        #pragma unroll
        for (int k4 = 0; k4 < DIM / 4; ++k4) {
            float4 t = reinterpret_cast<const float4*>(trow)[k4];
            d0 = fmaf(xr[4 * k4 + 0], t.x, d0);
            d1 = fmaf(xr[4 * k4 + 1], t.y, d1);
            d2 = fmaf(xr[4 * k4 + 2], t.z, d2);
            d3 = fmaf(xr[4 * k4 + 3], t.w, d3);
        }
        float dot = (d0 + d1) + (d2 + d3);
        float sq  = nx + nt_lds[jj] - 2.0f * dot;
        sq = fmaxf(sq, 0.0f);
        float kv = __expf(-0.5f * sq);
        acc = fmaf(kv, al_lds[jj], acc);
    }
    atomicAdd(&out[i], acc);
}

extern "C" void kernel_launch(void* const* d_in, const int* in_sizes, int n_in,
                              void* d_out, int out_size, void* d_ws, size_t ws_size,
                              hipStream_t stream) {
    const float* test_X      = (const float*)d_in[0];
    const float* train_X     = (const float*)d_in[1];
    const float* alphas      = (const float*)d_in[2];
    const float* lengthscale = (const float*)d_in[3];
    float* out = (float*)d_out;

    hipMemsetAsync(out, 0, NTEST * sizeof(float), stream);

    dim3 grid(NTEST / 256, NCHUNK);
    krr_main<<<grid, 256, 0, stream>>>(test_X, train_X, alphas, lengthscale, out);
}

// Round 3
// 170.638 us; speedup vs baseline: 1.3747x; 1.3747x over previous
//
#include <hip/hip_runtime.h>

#define NTEST  16384
#define NTRAIN 8192
#define DIM    64
#define MBLK   128                 // rows per block = 4 waves x 32
#define NSPLIT 8
#define NPB    (NTRAIN / NSPLIT)   // train cols per block

typedef _Float16 f16x8  __attribute__((ext_vector_type(8)));
typedef float    f32x16 __attribute__((ext_vector_type(16)));

#define LOSCALE 2048.0f
#define INV_LOSCALE (1.0f / 2048.0f)

// One wave per row. Rows [0,NTEST) = test_X -> A_hi/A_lo/nx.
// Rows [NTEST, NTEST+NTRAIN) = train_X -> B_hi/B_lo/nta={norm, alpha}.
// hi = f16(x) (RNE, 11-bit mantissa); lo = f16((x - hi) * 2048) (normalized).
__global__ __launch_bounds__(256) void krr_prep(
    const float* __restrict__ test_X, const float* __restrict__ train_X,
    const float* __restrict__ alphas,
    _Float16* __restrict__ A_hi, _Float16* __restrict__ A_lo,
    _Float16* __restrict__ B_hi, _Float16* __restrict__ B_lo,
    float* __restrict__ nx, float2* __restrict__ nta)
{
    int gwave = (blockIdx.x * 256 + threadIdx.x) >> 6;
    int lane  = threadIdx.x & 63;
    bool is_test = gwave < NTEST;
    int row = is_test ? gwave : gwave - NTEST;
    const float* src = is_test ? test_X : train_X;

    float x = src[(size_t)row * DIM + lane];
    _Float16 h = (_Float16)x;            // RNE to f16
    float r = x - (float)h;              // exact in fp32
    _Float16 L = (_Float16)(r * LOSCALE);

    if (is_test) {
        A_hi[(size_t)row * DIM + lane] = h;
        A_lo[(size_t)row * DIM + lane] = L;
    } else {
        B_hi[(size_t)row * DIM + lane] = h;
        B_lo[(size_t)row * DIM + lane] = L;
    }

    float s = x * x;
    s += __shfl_xor(s, 1);  s += __shfl_xor(s, 2);  s += __shfl_xor(s, 4);
    s += __shfl_xor(s, 8);  s += __shfl_xor(s, 16); s += __shfl_xor(s, 32);
    if (lane == 0) {
        if (is_test) nx[row] = s;
        else         nta[row] = make_float2(s, alphas[row]);
    }
}

// 4 waves/block, wave w owns 32 test rows; block streams NPB train cols in
// 32-col tiles. C1 accumulates hi*hi; C2 accumulates hi*lo + lo*hi (scaled by
// 2048). dot = C1 + C2/2048. Fused exp(c2*sq)*alpha epilogue. No LDS.
__global__ __launch_bounds__(256, 2) void krr_mfma(
    const _Float16* __restrict__ A_hi, const _Float16* __restrict__ A_lo,
    const _Float16* __restrict__ B_hi, const _Float16* __restrict__ B_lo,
    const float* __restrict__ nx, const float2* __restrict__ nta,
    const float* __restrict__ lengthscale, float* __restrict__ out)
{
    const int lane  = threadIdx.x & 63;
    const int wave  = threadIdx.x >> 6;
    const int rbase = blockIdx.x * MBLK + wave * 32;
    const int jbase = blockIdx.y * NPB;

    const float ls   = lengthscale[0];
    const float inv2 = 1.0f / (ls * ls);
    const float c2   = -0.5f * inv2;         // arg = c2 * sq_raw
    const float cLo  = inv2 * INV_LOSCALE;   // scale for C2 contribution

    const int arow = rbase + (lane & 31);
    const int koff = (lane >> 5) * 8;        // canonical k-map, same for A and B

    // A fragments (hi/lo), loop-invariant: 8 x 16B = 32 VGPRs
    f16x8 ah[4], aL[4];
    #pragma unroll
    for (int kk = 0; kk < 4; ++kk) {
        ah[kk] = *reinterpret_cast<const f16x8*>(A_hi + (size_t)arow * DIM + kk * 16 + koff);
        aL[kk] = *reinterpret_cast<const f16x8*>(A_lo + (size_t)arow * DIM + kk * 16 + koff);
    }

    // per-lane row constants: nx[row]*c2 for the 16 C/D rows this lane holds
    float nxc[16];
    #pragma unroll
    for (int r = 0; r < 16; ++r) {
        int row = (r & 3) + 8 * (r >> 2) + 4 * (lane >> 5);
        nxc[r] = nx[rbase + row] * c2;
    }

    float acc[16];
    #pragma unroll
    for (int r = 0; r < 16; ++r) acc[r] = 0.0f;

    const int bcol0 = jbase + (lane & 31);
    for (int jt = 0; jt < NPB; jt += 32) {
        const int j = bcol0 + jt;
        const _Float16* pbh = B_hi + (size_t)j * DIM + koff;
        const _Float16* pbl = B_lo + (size_t)j * DIM + koff;
        f16x8 bh[4], bL[4];
        #pragma unroll
        for (int kk = 0; kk < 4; ++kk) {
            bh[kk] = *reinterpret_cast<const f16x8*>(pbh + kk * 16);
            bL[kk] = *reinterpret_cast<const f16x8*>(pbl + kk * 16);
        }
        float2 na = nta[j];

        f32x16 C1 = {};
        f32x16 C2 = {};
        #pragma unroll
        for (int kk = 0; kk < 4; ++kk) {
            C1 = __builtin_amdgcn_mfma_f32_32x32x16_f16(ah[kk], bh[kk], C1, 0, 0, 0);
            C2 = __builtin_amdgcn_mfma_f32_32x32x16_f16(ah[kk], bL[kk], C2, 0, 0, 0);
            C2 = __builtin_amdgcn_mfma_f32_32x32x16_f16(aL[kk], bh[kk], C2, 0, 0, 0);
        }

        const float nb = nxc[0] * 0.0f + na.x * c2;  // ntc (keep simple)
        #pragma unroll
        for (int r = 0; r < 16; ++r) {
            float arg = fmaf(C1[r], inv2, nxc[r] + nb);  // c2*(nx+nt) + dot_hh
            arg = fmaf(C2[r], cLo, arg);                 // + cross-term correction
            arg = fminf(arg, 0.0f);                      // == -0.5*max(sq,0)
            float e = __expf(arg);
            acc[r] = fmaf(e, na.y, acc[r]);
        }
    }

    // Sum over the 32 train cols held across lanes of the same half.
    #pragma unroll
    for (int r = 0; r < 16; ++r) {
        float v = acc[r];
        v += __shfl_xor(v, 1);  v += __shfl_xor(v, 2);  v += __shfl_xor(v, 4);
        v += __shfl_xor(v, 8);  v += __shfl_xor(v, 16);
        if ((lane & 31) == 0) {
            int row = (r & 3) + 8 * (r >> 2) + 4 * (lane >> 5);
            atomicAdd(&out[rbase + row], v);
        }
    }
}

// ---------------- fallback (round-1 kernel, known-good) ----------------
#define TCHUNK 512
#define NCHUNK (NTRAIN / TCHUNK)
__global__ __launch_bounds__(256, 4) void krr_main(
    const float* __restrict__ test_X, const float* __restrict__ train_X,
    const float* __restrict__ alphas, const float* __restrict__ lengthscale,
    float* __restrict__ out)
{
    __shared__ float nt_lds[TCHUNK];
    __shared__ float al_lds[TCHUNK];
    const int tid = threadIdx.x;
    const int i   = blockIdx.x * 256 + tid;
    const int j0  = blockIdx.y * TCHUNK;
    const float ls   = lengthscale[0];
    const float inv2 = 1.0f / (ls * ls);
    for (int jj = tid; jj < TCHUNK; jj += 256) {
        const float4* tr = reinterpret_cast<const float4*>(train_X + (size_t)(j0 + jj) * DIM);
        float s = 0.f;
        #pragma unroll
        for (int k = 0; k < DIM / 4; ++k) {
            float4 t = tr[k];
            s += t.x * t.x + t.y * t.y + t.z * t.z + t.w * t.w;
        }
        nt_lds[jj] = s * inv2;
        al_lds[jj] = alphas[j0 + jj];
    }
    __syncthreads();
    float xr[DIM]; float nxv = 0.f;
    {
        const float4* xp = reinterpret_cast<const float4*>(test_X + (size_t)i * DIM);
        #pragma unroll
        for (int k = 0; k < DIM / 4; ++k) {
            float4 v = xp[k];
            xr[4*k+0] = v.x; xr[4*k+1] = v.y; xr[4*k+2] = v.z; xr[4*k+3] = v.w;
            nxv += v.x*v.x + v.y*v.y + v.z*v.z + v.w*v.w;
        }
        nxv *= inv2;
        #pragma unroll
        for (int k = 0; k < DIM; ++k) xr[k] *= inv2;
    }
    float acc = 0.f;
    for (int jj = 0; jj < TCHUNK; ++jj) {
        const float* trow = train_X + (size_t)(j0 + jj) * DIM;
        float d0 = 0.f, d1 = 0.f, d2 = 0.f, d3 = 0.f;
        #pragma unroll
        for (int k4 = 0; k4 < DIM / 4; ++k4) {
            float4 t = reinterpret_cast<const float4*>(trow)[k4];
            d0 = fmaf(xr[4*k4+0], t.x, d0);
            d1 = fmaf(xr[4*k4+1], t.y, d1);
            d2 = fmaf(xr[4*k4+2], t.z, d2);
            d3 = fmaf(xr[4*k4+3], t.w, d3);
        }
        float dot = (d0 + d1) + (d2 + d3);
        float sq  = nxv + nt_lds[jj] - 2.0f * dot;
        sq = fmaxf(sq, 0.0f);
        acc = fmaf(__expf(-0.5f * sq), al_lds[jj], acc);
    }
    atomicAdd(&out[i], acc);
}

extern "C" void kernel_launch(void* const* d_in, const int* in_sizes, int n_in,
                              void* d_out, int out_size, void* d_ws, size_t ws_size,
                              hipStream_t stream) {
    const float* test_X      = (const float*)d_in[0];
    const float* train_X     = (const float*)d_in[1];
    const float* alphas      = (const float*)d_in[2];
    const float* lengthscale = (const float*)d_in[3];
    float* out = (float*)d_out;

    hipMemsetAsync(out, 0, NTEST * sizeof(float), stream);

    const size_t need = (size_t)(NTEST + NTRAIN) * DIM * 2 * sizeof(_Float16)
                      + NTEST * sizeof(float) + NTRAIN * sizeof(float2);
    if (ws_size >= need) {
        _Float16* A_hi = (_Float16*)d_ws;
        _Float16* A_lo = A_hi + (size_t)NTEST * DIM;
        _Float16* B_hi = A_lo + (size_t)NTEST * DIM;
        _Float16* B_lo = B_hi + (size_t)NTRAIN * DIM;
        float*    nx   = (float*)(B_lo + (size_t)NTRAIN * DIM);
        float2*   nta  = (float2*)(nx + NTEST);

        krr_prep<<<(NTEST + NTRAIN) / 4, 256, 0, stream>>>(
            test_X, train_X, alphas, A_hi, A_lo, B_hi, B_lo, nx, nta);

        dim3 grid(NTEST / MBLK, NSPLIT);
        krr_mfma<<<grid, 256, 0, stream>>>(A_hi, A_lo, B_hi, B_lo, nx, nta,
                                           lengthscale, out);
    } else {
        dim3 grid(NTEST / 256, NCHUNK);
        krr_main<<<grid, 256, 0, stream>>>(test_X, train_X, alphas, lengthscale, out);
    }
}

// Round 4
// 163.437 us; speedup vs baseline: 1.4352x; 1.0441x over previous
//
#include <hip/hip_runtime.h>

#define NTEST  16384
#define NTRAIN 8192
#define DIM    64
#define MBLK   128                 // rows per block = 4 waves x 32
#define NSPLIT 16
#define NPB    (NTRAIN / NSPLIT)   // train cols per block = 512

typedef _Float16 f16x8  __attribute__((ext_vector_type(8)));
typedef float    f32x16 __attribute__((ext_vector_type(16)));

#define LOSCALE 2048.0f
#define INV_LOSCALE (1.0f / 2048.0f)

// One wave per row. Rows [0,NTEST) = test_X -> A_hi/A_lo/nx.
// Rows [NTEST, NTEST+NTRAIN) = train_X -> B_hi/B_lo/nta={norm, alpha}.
// hi = f16(x) (RNE); lo = f16((x - hi) * 2048) (normalized to avoid underflow).
__global__ __launch_bounds__(256) void krr_prep(
    const float* __restrict__ test_X, const float* __restrict__ train_X,
    const float* __restrict__ alphas,
    _Float16* __restrict__ A_hi, _Float16* __restrict__ A_lo,
    _Float16* __restrict__ B_hi, _Float16* __restrict__ B_lo,
    float* __restrict__ nx, float2* __restrict__ nta)
{
    int gwave = (blockIdx.x * 256 + threadIdx.x) >> 6;
    int lane  = threadIdx.x & 63;
    bool is_test = gwave < NTEST;
    int row = is_test ? gwave : gwave - NTEST;
    const float* src = is_test ? test_X : train_X;

    float x = src[(size_t)row * DIM + lane];
    _Float16 h = (_Float16)x;            // RNE to f16
    float r = x - (float)h;              // exact in fp32
    _Float16 L = (_Float16)(r * LOSCALE);

    if (is_test) {
        A_hi[(size_t)row * DIM + lane] = h;
        A_lo[(size_t)row * DIM + lane] = L;
    } else {
        B_hi[(size_t)row * DIM + lane] = h;
        B_lo[(size_t)row * DIM + lane] = L;
    }

    float s = x * x;
    s += __shfl_xor(s, 1);  s += __shfl_xor(s, 2);  s += __shfl_xor(s, 4);
    s += __shfl_xor(s, 8);  s += __shfl_xor(s, 16); s += __shfl_xor(s, 32);
    if (lane == 0) {
        if (is_test) nx[row] = s;
        else         nta[row] = make_float2(s, alphas[row]);
    }
}

// 4 waves/block, wave w owns 32 test rows; block streams NPB train cols in
// 32-col tiles. C1 = hi*hi; C2a = hi*lo; C2b = lo*hi (lo pre-scaled by 2048).
// dot = C1 + (C2a+C2b)/2048. Fused exp(c2*sq)*alpha epilogue. No LDS.
// Three independent 4-deep MFMA chains for ILP; VGPR ~88 -> 5 waves/SIMD.
__global__ __launch_bounds__(256, 4) void krr_mfma(
    const _Float16* __restrict__ A_hi, const _Float16* __restrict__ A_lo,
    const _Float16* __restrict__ B_hi, const _Float16* __restrict__ B_lo,
    const float* __restrict__ nx, const float2* __restrict__ nta,
    const float* __restrict__ lengthscale, float* __restrict__ out)
{
    const int lane  = threadIdx.x & 63;
    const int wave  = threadIdx.x >> 6;
    const int rbase = blockIdx.x * MBLK + wave * 32;
    const int jbase = blockIdx.y * NPB;

    const float ls   = lengthscale[0];
    const float inv2 = 1.0f / (ls * ls);
    const float c2   = -0.5f * inv2;         // arg = c2 * sq_raw
    const float cLo  = inv2 * INV_LOSCALE;   // scale for cross-term accumulators

    const int arow = rbase + (lane & 31);
    const int koff = (lane >> 5) * 8;        // canonical k-map, same for A and B

    // A fragments (hi/lo), loop-invariant: 8 x 16B = 32 VGPRs
    f16x8 ah[4], aL[4];
    #pragma unroll
    for (int kk = 0; kk < 4; ++kk) {
        ah[kk] = *reinterpret_cast<const f16x8*>(A_hi + (size_t)arow * DIM + kk * 16 + koff);
        aL[kk] = *reinterpret_cast<const f16x8*>(A_lo + (size_t)arow * DIM + kk * 16 + koff);
    }

    // per-lane row constants: nx[row]*c2 for the 16 C/D rows this lane holds
    float nxc[16];
    #pragma unroll
    for (int r = 0; r < 16; ++r) {
        int row = (r & 3) + 8 * (r >> 2) + 4 * (lane >> 5);
        nxc[r] = nx[rbase + row] * c2;
    }

    float acc[16];
    #pragma unroll
    for (int r = 0; r < 16; ++r) acc[r] = 0.0f;

    const int bcol0 = jbase + (lane & 31);
    for (int jt = 0; jt < NPB; jt += 32) {
        const int j = bcol0 + jt;
        const _Float16* pbh = B_hi + (size_t)j * DIM + koff;
        const _Float16* pbl = B_lo + (size_t)j * DIM + koff;
        f16x8 bh[4], bL[4];
        #pragma unroll
        for (int kk = 0; kk < 4; ++kk) {
            bh[kk] = *reinterpret_cast<const f16x8*>(pbh + kk * 16);
            bL[kk] = *reinterpret_cast<const f16x8*>(pbl + kk * 16);
        }
        float2 na = nta[j];

        f32x16 C1  = {};
        f32x16 C2a = {};
        f32x16 C2b = {};
        #pragma unroll
        for (int kk = 0; kk < 4; ++kk) {
            C1  = __builtin_amdgcn_mfma_f32_32x32x16_f16(ah[kk], bh[kk], C1,  0, 0, 0);
            C2a = __builtin_amdgcn_mfma_f32_32x32x16_f16(ah[kk], bL[kk], C2a, 0, 0, 0);
            C2b = __builtin_amdgcn_mfma_f32_32x32x16_f16(aL[kk], bh[kk], C2b, 0, 0, 0);
        }

        const float ntc = na.x * c2;
        #pragma unroll
        for (int r = 0; r < 16; ++r) {
            float arg = fmaf(C1[r], inv2, nxc[r] + ntc);   // c2*(nx+nt) + hi.hi
            arg = fmaf(C2a[r] + C2b[r], cLo, arg);         // + cross terms
            arg = fminf(arg, 0.0f);                        // == -0.5*max(sq,0)
            float e = __expf(arg);
            acc[r] = fmaf(e, na.y, acc[r]);
        }
    }

    // Sum over the 32 train cols held across lanes of the same half.
    #pragma unroll
    for (int r = 0; r < 16; ++r) {
        float v = acc[r];
        v += __shfl_xor(v, 1);  v += __shfl_xor(v, 2);  v += __shfl_xor(v, 4);
        v += __shfl_xor(v, 8);  v += __shfl_xor(v, 16);
        if ((lane & 31) == 0) {
            int row = (r & 3) + 8 * (r >> 2) + 4 * (lane >> 5);
            atomicAdd(&out[rbase + row], v);
        }
    }
}

// ---------------- fallback (round-1 kernel, known-good) ----------------
#define TCHUNK 512
#define NCHUNK (NTRAIN / TCHUNK)
__global__ __launch_bounds__(256, 4) void krr_main(
    const float* __restrict__ test_X, const float* __restrict__ train_X,
    const float* __restrict__ alphas, const float* __restrict__ lengthscale,
    float* __restrict__ out)
{
    __shared__ float nt_lds[TCHUNK];
    __shared__ float al_lds[TCHUNK];
    const int tid = threadIdx.x;
    const int i   = blockIdx.x * 256 + tid;
    const int j0  = blockIdx.y * TCHUNK;
    const float ls   = lengthscale[0];
    const float inv2 = 1.0f / (ls * ls);
    for (int jj = tid; jj < TCHUNK; jj += 256) {
        const float4* tr = reinterpret_cast<const float4*>(train_X + (size_t)(j0 + jj) * DIM);
        float s = 0.f;
        #pragma unroll
        for (int k = 0; k < DIM / 4; ++k) {
            float4 t = tr[k];
            s += t.x * t.x + t.y * t.y + t.z * t.z + t.w * t.w;
        }
        nt_lds[jj] = s * inv2;
        al_lds[jj] = alphas[j0 + jj];
    }
    __syncthreads();
    float xr[DIM]; float nxv = 0.f;
    {
        const float4* xp = reinterpret_cast<const float4*>(test_X + (size_t)i * DIM);
        #pragma unroll
        for (int k = 0; k < DIM / 4; ++k) {
            float4 v = xp[k];
            xr[4*k+0] = v.x; xr[4*k+1] = v.y; xr[4*k+2] = v.z; xr[4*k+3] = v.w;
            nxv += v.x*v.x + v.y*v.y + v.z*v.z + v.w*v.w;
        }
        nxv *= inv2;
        #pragma unroll
        for (int k = 0; k < DIM; ++k) xr[k] *= inv2;
    }
    float acc = 0.f;
    for (int jj = 0; jj < TCHUNK; ++jj) {
        const float* trow = train_X + (size_t)(j0 + jj) * DIM;
        float d0 = 0.f, d1 = 0.f, d2 = 0.f, d3 = 0.f;
        #pragma unroll
        for (int k4 = 0; k4 < DIM / 4; ++k4) {
            float4 t = reinterpret_cast<const float4*>(trow)[k4];
            d0 = fmaf(xr[4*k4+0], t.x, d0);
            d1 = fmaf(xr[4*k4+1], t.y, d1);
            d2 = fmaf(xr[4*k4+2], t.z, d2);
            d3 = fmaf(xr[4*k4+3], t.w, d3);
        }
        float dot = (d0 + d1) + (d2 + d3);
        float sq  = nxv + nt_lds[jj] - 2.0f * dot;
        sq = fmaxf(sq, 0.0f);
        acc = fmaf(__expf(-0.5f * sq), al_lds[jj], acc);
    }
    atomicAdd(&out[i], acc);
}

extern "C" void kernel_launch(void* const* d_in, const int* in_sizes, int n_in,
                              void* d_out, int out_size, void* d_ws, size_t ws_size,
                              hipStream_t stream) {
    const float* test_X      = (const float*)d_in[0];
    const float* train_X     = (const float*)d_in[1];
    const float* alphas      = (const float*)d_in[2];
    const float* lengthscale = (const float*)d_in[3];
    float* out = (float*)d_out;

    hipMemsetAsync(out, 0, NTEST * sizeof(float), stream);

    const size_t need = (size_t)(NTEST + NTRAIN) * DIM * 2 * sizeof(_Float16)
                      + NTEST * sizeof(float) + NTRAIN * sizeof(float2);
    if (ws_size >= need) {
        _Float16* A_hi = (_Float16*)d_ws;
        _Float16* A_lo = A_hi + (size_t)NTEST * DIM;
        _Float16* B_hi = A_lo + (size_t)NTEST * DIM;
        _Float16* B_lo = B_hi + (size_t)NTRAIN * DIM;
        float*    nx   = (float*)(B_lo + (size_t)NTRAIN * DIM);
        float2*   nta  = (float2*)(nx + NTEST);

        krr_prep<<<(NTEST + NTRAIN) / 4, 256, 0, stream>>>(
            test_X, train_X, alphas, A_hi, A_lo, B_hi, B_lo, nx, nta);

        dim3 grid(NTEST / MBLK, NSPLIT);
        krr_mfma<<<grid, 256, 0, stream>>>(A_hi, A_lo, B_hi, B_lo, nx, nta,
                                           lengthscale, out);
    } else {
        dim3 grid(NTEST / 256, NCHUNK);
        krr_main<<<grid, 256, 0, stream>>>(test_X, train_X, alphas, lengthscale, out);
    }
}

// Round 5
// 117.358 us; speedup vs baseline: 1.9988x; 1.3926x over previous
//
#include <hip/hip_runtime.h>

#define NTEST  16384
#define NTRAIN 8192
#define DIM    64
#define NSPLIT 8
#define NPB    (NTRAIN / NSPLIT)   // 1024 train cols per block
#define TPW    (NPB / 32 / 4)      // 8 col-tiles per wave

typedef _Float16 f16x8  __attribute__((ext_vector_type(8)));
typedef float    f32x16 __attribute__((ext_vector_type(16)));

#define LOSCALE     2048.0f
#define INV_LOSCALE (1.0f / 2048.0f)
#define LOG2E       1.4426950408889634f

// One wave per row. Rows [0,NTEST) = test_X -> A_hi/A_lo (row-major) + nx.
// Rows [NTEST,..) = train_X -> B_hi/B_lo in TILE-MAJOR fragment layout + nta.
// hi = f16(x) RNE; lo = f16((x-hi)*2048).
// Tile-major: for train row r, dim k:
//   flat = (r>>5)*2048 + (k>>4)*512 + (((k>>3)&1)*32 + (r&31))*8 + (k&7)
// so the mfma kernel's fragment load kk for tile t is the contiguous 1KB
// block at B + t*2048 + kk*512 + lane*8 (lane&31 = col, lane>>5 = k-half).
__global__ __launch_bounds__(256) void krr_prep(
    const float* __restrict__ test_X, const float* __restrict__ train_X,
    const float* __restrict__ alphas,
    _Float16* __restrict__ A_hi, _Float16* __restrict__ A_lo,
    _Float16* __restrict__ B_hi, _Float16* __restrict__ B_lo,
    float* __restrict__ nx, float2* __restrict__ nta)
{
    int gwave = (blockIdx.x * 256 + threadIdx.x) >> 6;
    int lane  = threadIdx.x & 63;           // = dim index k
    bool is_test = gwave < NTEST;
    int row = is_test ? gwave : gwave - NTEST;
    const float* src = is_test ? test_X : train_X;

    float x = src[(size_t)row * DIM + lane];
    _Float16 h = (_Float16)x;                // RNE to f16
    float r = x - (float)h;                  // exact in fp32
    _Float16 L = (_Float16)(r * LOSCALE);

    if (is_test) {
        A_hi[(size_t)row * DIM + lane] = h;
        A_lo[(size_t)row * DIM + lane] = L;
    } else {
        int t  = row >> 5, lr = row & 31;
        int kk = lane >> 4, hi = (lane >> 3) & 1, e = lane & 7;
        size_t dst = (size_t)t * 2048 + (size_t)kk * 512 + (size_t)(hi * 32 + lr) * 8 + e;
        B_hi[dst] = h;
        B_lo[dst] = L;
    }

    float s = x * x;
    s += __shfl_xor(s, 1);  s += __shfl_xor(s, 2);  s += __shfl_xor(s, 4);
    s += __shfl_xor(s, 8);  s += __shfl_xor(s, 16); s += __shfl_xor(s, 32);
    if (lane == 0) {
        if (is_test) nx[row] = s;
        else         nta[row] = make_float2(s, alphas[row]);
    }
}

// Block = 32 test rows x NPB train cols; 4 waves SPLIT THE COLS (disjoint
// 256-col ranges) so each B byte is loaded once per block, via fully
// contiguous 1KB fragment loads (tile-major layout). All waves share the
// same 32 A rows. C1 = hi*hi; C2a = hi*lo; C2b = lo*hi (lo scaled by 2048).
// arg(log2-domain) = cn*(nx+nt) + s1*C1 + sLo*(C2a+C2b); K = exp2(min(arg,0)).
__global__ __launch_bounds__(256, 3) void krr_mfma(
    const _Float16* __restrict__ A_hi, const _Float16* __restrict__ A_lo,
    const _Float16* __restrict__ B_hi, const _Float16* __restrict__ B_lo,
    const float* __restrict__ nx, const float2* __restrict__ nta,
    const float* __restrict__ lengthscale, float* __restrict__ out)
{
    const int lane  = threadIdx.x & 63;
    const int wave  = threadIdx.x >> 6;
    const int rbase = blockIdx.x * 32;
    const int t0    = blockIdx.y * (NPB / 32) + wave * TPW;

    const float ls   = lengthscale[0];
    const float inv2 = 1.0f / (ls * ls);
    const float s1   = inv2 * LOG2E;                 // C1 scale (dot term)
    const float sLo  = inv2 * INV_LOSCALE * LOG2E;   // cross-term scale
    const float cn   = -0.5f * inv2 * LOG2E;         // norm scale

    const int arow = rbase + (lane & 31);
    const int koff = (lane >> 5) * 8;        // canonical k-map, same for A and B

    // A fragments (hi/lo), loop-invariant: 8 x 16B = 32 VGPRs
    f16x8 ah[4], aL[4];
    #pragma unroll
    for (int kk = 0; kk < 4; ++kk) {
        ah[kk] = *reinterpret_cast<const f16x8*>(A_hi + (size_t)arow * DIM + kk * 16 + koff);
        aL[kk] = *reinterpret_cast<const f16x8*>(A_lo + (size_t)arow * DIM + kk * 16 + koff);
    }

    // per-lane row constants: nx[row]*cn for the 16 C/D rows this lane holds
    float nxc[16];
    #pragma unroll
    for (int r = 0; r < 16; ++r) {
        int row = (r & 3) + 8 * (r >> 2) + 4 * (lane >> 5);
        nxc[r] = nx[rbase + row] * cn;
    }

    float acc[16];
    #pragma unroll
    for (int r = 0; r < 16; ++r) acc[r] = 0.0f;

    for (int t = t0; t < t0 + TPW; ++t) {
        // Fragment loads: fully contiguous 1KB per instruction.
        const _Float16* ph = B_hi + (size_t)t * 2048 + (size_t)lane * 8;
        const _Float16* pl = B_lo + (size_t)t * 2048 + (size_t)lane * 8;
        f16x8 bh[4], bL[4];
        #pragma unroll
        for (int kk = 0; kk < 4; ++kk) {
            bh[kk] = *reinterpret_cast<const f16x8*>(ph + kk * 512);
            bL[kk] = *reinterpret_cast<const f16x8*>(pl + kk * 512);
        }
        float2 na = nta[t * 32 + (lane & 31)];

        f32x16 C1  = {};
        f32x16 C2a = {};
        f32x16 C2b = {};
        #pragma unroll
        for (int kk = 0; kk < 4; ++kk) {
            C1  = __builtin_amdgcn_mfma_f32_32x32x16_f16(ah[kk], bh[kk], C1,  0, 0, 0);
            C2a = __builtin_amdgcn_mfma_f32_32x32x16_f16(ah[kk], bL[kk], C2a, 0, 0, 0);
            C2b = __builtin_amdgcn_mfma_f32_32x32x16_f16(aL[kk], bh[kk], C2b, 0, 0, 0);
        }

        const float ntc = na.x * cn;
        #pragma unroll
        for (int r = 0; r < 16; ++r) {
            float arg = fmaf(C1[r], s1, nxc[r] + ntc);   // log2-domain
            arg = fmaf(C2a[r] + C2b[r], sLo, arg);       // + cross terms
            arg = fminf(arg, 0.0f);                      // == max(sq,0) clamp
            acc[r] = fmaf(exp2f(arg), na.y, acc[r]);
        }
    }

    // Sum over the 32 train cols held across lanes of the same half.
    #pragma unroll
    for (int r = 0; r < 16; ++r) {
        float v = acc[r];
        v += __shfl_xor(v, 1);  v += __shfl_xor(v, 2);  v += __shfl_xor(v, 4);
        v += __shfl_xor(v, 8);  v += __shfl_xor(v, 16);
        if ((lane & 31) == 0) {
            int row = (r & 3) + 8 * (r >> 2) + 4 * (lane >> 5);
            atomicAdd(&out[rbase + row], v);
        }
    }
}

// ---------------- fallback (round-1 kernel, known-good) ----------------
#define TCHUNK 512
#define NCHUNK (NTRAIN / TCHUNK)
__global__ __launch_bounds__(256, 4) void krr_main(
    const float* __restrict__ test_X, const float* __restrict__ train_X,
    const float* __restrict__ alphas, const float* __restrict__ lengthscale,
    float* __restrict__ out)
{
    __shared__ float nt_lds[TCHUNK];
    __shared__ float al_lds[TCHUNK];
    const int tid = threadIdx.x;
    const int i   = blockIdx.x * 256 + tid;
    const int j0  = blockIdx.y * TCHUNK;
    const float ls   = lengthscale[0];
    const float inv2 = 1.0f / (ls * ls);
    for (int jj = tid; jj < TCHUNK; jj += 256) {
        const float4* tr = reinterpret_cast<const float4*>(train_X + (size_t)(j0 + jj) * DIM);
        float s = 0.f;
        #pragma unroll
        for (int k = 0; k < DIM / 4; ++k) {
            float4 t = tr[k];
            s += t.x * t.x + t.y * t.y + t.z * t.z + t.w * t.w;
        }
        nt_lds[jj] = s * inv2;
        al_lds[jj] = alphas[j0 + jj];
    }
    __syncthreads();
    float xr[DIM]; float nxv = 0.f;
    {
        const float4* xp = reinterpret_cast<const float4*>(test_X + (size_t)i * DIM);
        #pragma unroll
        for (int k = 0; k < DIM / 4; ++k) {
            float4 v = xp[k];
            xr[4*k+0] = v.x; xr[4*k+1] = v.y; xr[4*k+2] = v.z; xr[4*k+3] = v.w;
            nxv += v.x*v.x + v.y*v.y + v.z*v.z + v.w*v.w;
        }
        nxv *= inv2;
        #pragma unroll
        for (int k = 0; k < DIM; ++k) xr[k] *= inv2;
    }
    float acc = 0.f;
    for (int jj = 0; jj < TCHUNK; ++jj) {
        const float* trow = train_X + (size_t)(j0 + jj) * DIM;
        float d0 = 0.f, d1 = 0.f, d2 = 0.f, d3 = 0.f;
        #pragma unroll
        for (int k4 = 0; k4 < DIM / 4; ++k4) {
            float4 t = reinterpret_cast<const float4*>(trow)[k4];
            d0 = fmaf(xr[4*k4+0], t.x, d0);
            d1 = fmaf(xr[4*k4+1], t.y, d1);
            d2 = fmaf(xr[4*k4+2], t.z, d2);
            d3 = fmaf(xr[4*k4+3], t.w, d3);
        }
        float dot = (d0 + d1) + (d2 + d3);
        float sq  = nxv + nt_lds[jj] - 2.0f * dot;
        sq = fmaxf(sq, 0.0f);
        acc = fmaf(__expf(-0.5f * sq), al_lds[jj], acc);
    }
    atomicAdd(&out[i], acc);
}

extern "C" void kernel_launch(void* const* d_in, const int* in_sizes, int n_in,
                              void* d_out, int out_size, void* d_ws, size_t ws_size,
                              hipStream_t stream) {
    const float* test_X      = (const float*)d_in[0];
    const float* train_X     = (const float*)d_in[1];
    const float* alphas      = (const float*)d_in[2];
    const float* lengthscale = (const float*)d_in[3];
    float* out = (float*)d_out;

    hipMemsetAsync(out, 0, NTEST * sizeof(float), stream);

    const size_t need = (size_t)(NTEST + NTRAIN) * DIM * 2 * sizeof(_Float16)
                      + NTEST * sizeof(float) + NTRAIN * sizeof(float2);
    if (ws_size >= need) {
        _Float16* A_hi = (_Float16*)d_ws;
        _Float16* A_lo = A_hi + (size_t)NTEST * DIM;
        _Float16* B_hi = A_lo + (size_t)NTEST * DIM;
        _Float16* B_lo = B_hi + (size_t)NTRAIN * DIM;
        float*    nx   = (float*)(B_lo + (size_t)NTRAIN * DIM);
        float2*   nta  = (float2*)(nx + NTEST);

        krr_prep<<<(NTEST + NTRAIN) / 4, 256, 0, stream>>>(
            test_X, train_X, alphas, A_hi, A_lo, B_hi, B_lo, nx, nta);

        dim3 grid(NTEST / 32, NSPLIT);
        krr_mfma<<<grid, 256, 0, stream>>>(A_hi, A_lo, B_hi, B_lo, nx, nta,
                                           lengthscale, out);
    } else {
        dim3 grid(NTEST / 256, NCHUNK);
        krr_main<<<grid, 256, 0, stream>>>(test_X, train_X, alphas, lengthscale, out);
    }
}